// Round 4
// baseline (714.177 us; speedup 1.0000x reference)
//
#include <hip/hip_runtime.h>
#include <cstdint>
#include <cstddef>

static constexpr int Nn = 20000;
static constexpr int Ee = 320000;

__device__ __forceinline__ float lrelu02(float x){ return fmaxf(x, 0.2f*x); }

// ---------------- CSR build ----------------
__global__ void k_count(const int* __restrict__ dst, int* __restrict__ cnt){
  int e = blockIdx.x*256 + threadIdx.x;
  if (e < Ee) atomicAdd(&cnt[dst[e]], 1);
}

__global__ void k_scan(const int* __restrict__ cnt, int* __restrict__ row_start,
                       float* __restrict__ dinv){
  __shared__ int part[1024];
  int tid = threadIdx.x;
  const int PER = 20;
  int base = tid*PER;
  int s = 0;
  for (int i = 0; i < PER; ++i){ int idx = base+i; if (idx < Nn) s += cnt[idx]; }
  part[tid] = s; __syncthreads();
  for (int off = 1; off < 1024; off <<= 1){
    int v = (tid >= off) ? part[tid-off] : 0;
    __syncthreads();
    part[tid] += v;
    __syncthreads();
  }
  int run = (tid == 0) ? 0 : part[tid-1];
  for (int i = 0; i < PER; ++i){
    int idx = base+i;
    if (idx < Nn){
      row_start[idx] = run;
      int c = cnt[idx];
      run += c;
      dinv[idx] = rsqrtf((float)(c+1));
    }
  }
  if (tid == 1023) row_start[Nn] = run;
}

__global__ void k_scatter(const int* __restrict__ src, const int* __restrict__ dst,
                          const int* __restrict__ row_start, int* __restrict__ fill,
                          int* __restrict__ csr){
  int e = blockIdx.x*256 + threadIdx.x;
  if (e < Ee){
    int d = dst[e];
    int pos = row_start[d] + atomicAdd(&fill[d], 1);
    csr[pos] = src[e];
  }
}

// ---------------- GCN aggregation (batched gather): out[v] = dv*sum du*h[u] + dv^2*h[v] ----------------
template<int C, bool POST>
__global__ __launch_bounds__(256) void k_gcn_agg(
    const float* __restrict__ h, const float* __restrict__ dinv,
    const int* __restrict__ row_start, const int* __restrict__ csr,
    const float* __restrict__ bias, const float* __restrict__ skip,
    float* __restrict__ out){
  int v = blockIdx.x*4 + (threadIdx.x >> 6);
  int lane = threadIdx.x & 63;
  int s = row_start[v], e = row_start[v+1];
  float dv = dinv[v];
  const int c = (C==32) ? (lane & 31) : ((C==128) ? lane*2 : lane);

  float a0 = 0.f, a1 = 0.f;
  for (int base = s; base < e; base += 64){
    int i = base + lane;
    int u = 0; float du = 0.f;
    if (i < e){ u = csr[i]; du = dinv[u]; }
    int cnt = min(64, e - base);
    int j = 0;
    for (; j + 4 <= cnt; j += 4){
      int u0=__shfl(u,j), u1=__shfl(u,j+1), u2=__shfl(u,j+2), u3=__shfl(u,j+3);
      float d0=__shfl(du,j), d1=__shfl(du,j+1), d2=__shfl(du,j+2), d3=__shfl(du,j+3);
      if constexpr (C == 128){
        float2 t0 = *(const float2*)&h[(size_t)u0*128 + c];
        float2 t1 = *(const float2*)&h[(size_t)u1*128 + c];
        float2 t2 = *(const float2*)&h[(size_t)u2*128 + c];
        float2 t3 = *(const float2*)&h[(size_t)u3*128 + c];
        a0=fmaf(d0,t0.x,a0); a1=fmaf(d0,t0.y,a1);
        a0=fmaf(d1,t1.x,a0); a1=fmaf(d1,t1.y,a1);
        a0=fmaf(d2,t2.x,a0); a1=fmaf(d2,t2.y,a1);
        a0=fmaf(d3,t3.x,a0); a1=fmaf(d3,t3.y,a1);
      } else {
        float t0 = h[(size_t)u0*C + c];
        float t1 = h[(size_t)u1*C + c];
        float t2 = h[(size_t)u2*C + c];
        float t3 = h[(size_t)u3*C + c];
        a0=fmaf(d0,t0,a0); a0=fmaf(d1,t1,a0); a0=fmaf(d2,t2,a0); a0=fmaf(d3,t3,a0);
      }
    }
    for (; j < cnt; ++j){
      int uj = __shfl(u,j); float dj = __shfl(du,j);
      if constexpr (C == 128){
        float2 t = *(const float2*)&h[(size_t)uj*128 + c];
        a0 = fmaf(dj, t.x, a0); a1 = fmaf(dj, t.y, a1);
      } else {
        a0 = fmaf(dj, h[(size_t)uj*C + c], a0);
      }
    }
  }

  if constexpr (C == 128){
    float2 hv = *(const float2*)&h[(size_t)v*128 + c];
    float vx = fmaf(a0, dv, hv.x*dv*dv);
    float vy = fmaf(a1, dv, hv.y*dv*dv);
    if constexpr (POST){
      float2 bv = *(const float2*)&bias[c];
      float2 sk = *(const float2*)&skip[(size_t)v*128 + c];
      vx = fmaxf(vx + bv.x, 0.f) + sk.x;
      vy = fmaxf(vy + bv.y, 0.f) + sk.y;
    }
    *(float2*)&out[(size_t)v*128 + c] = make_float2(vx, vy);
  } else if constexpr (C == 64){
    float val = fmaf(a0, dv, h[(size_t)v*64 + c]*dv*dv);
    if constexpr (POST){
      val = fmaxf(val + bias[c], 0.f) + skip[(size_t)v*64 + c];
    }
    out[(size_t)v*64 + c] = val;
  } else { // C == 32
    float val = fmaf(a0, dv, h[(size_t)v*32 + c]*dv*dv);
    if (lane < 32) out[(size_t)v*32 + c] = val;
  }
}

// ---------------- fold attention vectors through W ----------------
template<int INC, int C>
__global__ void k_fold(const float* __restrict__ W, const float* __restrict__ as_,
                       const float* __restrict__ ad_, float* __restrict__ wsF,
                       float* __restrict__ wdF){
  int h = threadIdx.x >> 6, lane = threadIdx.x & 63;
  for (int k = lane; k < INC; k += 64){
    float s = 0.f, d = 0.f;
    #pragma unroll 4
    for (int c = 0; c < C; ++c){
      float wv = W[(size_t)k*(4*C) + h*C + c];
      s = fmaf(wv, as_[h*C + c], s);
      d = fmaf(wv, ad_[h*C + c], d);
    }
    wsF[h*INC + k] = s;
    wdF[h*INC + k] = d;
  }
}

// ---------------- attention coefficients from the INPUT ----------------
template<int INC>
__global__ __launch_bounds__(256) void k_attn_in(
    const float* __restrict__ X, const float* __restrict__ wsF, const float* __restrict__ wdF,
    float* __restrict__ aS, float* __restrict__ aD){
  int v = blockIdx.x*4 + (threadIdx.x >> 6);
  int lane = threadIdx.x & 63;
  float x0 = X[(size_t)v*INC + lane];
  float x1 = (INC == 128) ? X[(size_t)v*INC + 64 + lane] : 0.f;
  float s[4], d[4];
  #pragma unroll
  for (int h = 0; h < 4; ++h){
    s[h] = x0*wsF[h*INC + lane];
    d[h] = x0*wdF[h*INC + lane];
    if constexpr (INC == 128){
      s[h] = fmaf(x1, wsF[h*INC + 64 + lane], s[h]);
      d[h] = fmaf(x1, wdF[h*INC + 64 + lane], d[h]);
    }
  }
  #pragma unroll
  for (int off = 32; off; off >>= 1){
    #pragma unroll
    for (int h = 0; h < 4; ++h){
      s[h] += __shfl_xor(s[h], off);
      d[h] += __shfl_xor(d[h], off);
    }
  }
  if (lane == 0){
    *(float4*)&aS[v*4] = make_float4(s[0], s[1], s[2], s[3]);
    *(float4*)&aD[v*4] = make_float4(d[0], d[1], d[2], d[3]);
  }
}

// ---------------- GAT aggregation, batched + single-pass (unnormalized acc, normalize at end) ----------------
template<int INC>   // 128 (e3) or 64 (d3)
__global__ __launch_bounds__(256) void k_gat_agg_in(
    const float* __restrict__ X, const float* __restrict__ aS, const float* __restrict__ aD,
    const int* __restrict__ row_start, const int* __restrict__ csr,
    float* __restrict__ agg){
  int v = blockIdx.x*4 + (threadIdx.x >> 6);
  int lane = threadIdx.x & 63;
  int s0 = row_start[v], e0 = row_start[v+1];

  float4 tD = *(const float4*)&aD[v*4];
  float ad0=tD.x, ad1=tD.y, ad2=tD.z, ad3=tD.w;
  float4 tS = *(const float4*)&aS[v*4];
  float ls0=lrelu02(tS.x+ad0), ls1=lrelu02(tS.y+ad1), ls2=lrelu02(tS.z+ad2), ls3=lrelu02(tS.w+ad3);

  // pass 1: per-head max (lane-parallel, max-only)
  float m0=ls0, m1=ls1, m2=ls2, m3=ls3;
  for (int i = s0 + lane; i < e0; i += 64){
    int u = csr[i];
    float4 a4 = *(const float4*)&aS[u*4];
    m0 = fmaxf(m0, lrelu02(a4.x+ad0));
    m1 = fmaxf(m1, lrelu02(a4.y+ad1));
    m2 = fmaxf(m2, lrelu02(a4.z+ad2));
    m3 = fmaxf(m3, lrelu02(a4.w+ad3));
  }
  #pragma unroll
  for (int off = 32; off; off >>= 1){
    m0 = fmaxf(m0, __shfl_xor(m0, off));
    m1 = fmaxf(m1, __shfl_xor(m1, off));
    m2 = fmaxf(m2, __shfl_xor(m2, off));
    m3 = fmaxf(m3, __shfl_xor(m3, off));
  }

  // main pass: per-64-edge batch, lane-parallel exp; broadcast accumulate
  float sd0=0.f, sd1=0.f, sd2=0.f, sd3=0.f;
  float2 acc0={0,0}, acc1={0,0}, acc2={0,0}, acc3={0,0};  // INC==128
  float ac0=0.f, ac1=0.f, ac2=0.f, ac3=0.f;               // INC==64
  const int c2 = lane*2;

  for (int base = s0; base < e0; base += 64){
    int i = base + lane;
    int u = 0; float e0v=0.f, e1v=0.f, e2v=0.f, e3v=0.f;
    if (i < e0){
      u = csr[i];
      float4 a4 = *(const float4*)&aS[u*4];
      e0v = __expf(lrelu02(a4.x+ad0) - m0);
      e1v = __expf(lrelu02(a4.y+ad1) - m1);
      e2v = __expf(lrelu02(a4.z+ad2) - m2);
      e3v = __expf(lrelu02(a4.w+ad3) - m3);
      sd0 += e0v; sd1 += e1v; sd2 += e2v; sd3 += e3v;
    }
    int cnt = min(64, e0 - base);
    #pragma unroll 2
    for (int j = 0; j < cnt; ++j){
      int uj = __shfl(u, j);
      float f0=__shfl(e0v,j), f1=__shfl(e1v,j), f2=__shfl(e2v,j), f3=__shfl(e3v,j);
      if constexpr (INC == 128){
        float2 xu = *(const float2*)&X[(size_t)uj*128 + c2];
        acc0.x=fmaf(f0,xu.x,acc0.x); acc0.y=fmaf(f0,xu.y,acc0.y);
        acc1.x=fmaf(f1,xu.x,acc1.x); acc1.y=fmaf(f1,xu.y,acc1.y);
        acc2.x=fmaf(f2,xu.x,acc2.x); acc2.y=fmaf(f2,xu.y,acc2.y);
        acc3.x=fmaf(f3,xu.x,acc3.x); acc3.y=fmaf(f3,xu.y,acc3.y);
      } else {
        float xu = X[(size_t)uj*64 + lane];
        ac0=fmaf(f0,xu,ac0); ac1=fmaf(f1,xu,ac1); ac2=fmaf(f2,xu,ac2); ac3=fmaf(f3,xu,ac3);
      }
    }
  }

  #pragma unroll
  for (int off = 32; off; off >>= 1){
    sd0 += __shfl_xor(sd0, off);
    sd1 += __shfl_xor(sd1, off);
    sd2 += __shfl_xor(sd2, off);
    sd3 += __shfl_xor(sd3, off);
  }
  float es0=__expf(ls0-m0), es1=__expf(ls1-m1), es2=__expf(ls2-m2), es3=__expf(ls3-m3);
  float r0=1.f/(sd0+es0), r1=1.f/(sd1+es1), r2=1.f/(sd2+es2), r3=1.f/(sd3+es3);

  if constexpr (INC == 128){
    float2 xv = *(const float2*)&X[(size_t)v*128 + c2];
    float2 o;
    o.x=(acc0.x+es0*xv.x)*r0; o.y=(acc0.y+es0*xv.y)*r0; *(float2*)&agg[(size_t)v*512 +   0 + c2]=o;
    o.x=(acc1.x+es1*xv.x)*r1; o.y=(acc1.y+es1*xv.y)*r1; *(float2*)&agg[(size_t)v*512 + 128 + c2]=o;
    o.x=(acc2.x+es2*xv.x)*r2; o.y=(acc2.y+es2*xv.y)*r2; *(float2*)&agg[(size_t)v*512 + 256 + c2]=o;
    o.x=(acc3.x+es3*xv.x)*r3; o.y=(acc3.y+es3*xv.y)*r3; *(float2*)&agg[(size_t)v*512 + 384 + c2]=o;
  } else {
    float xv = X[(size_t)v*64 + lane];
    agg[(size_t)v*256 +   0 + lane] = (ac0+es0*xv)*r0;
    agg[(size_t)v*256 +  64 + lane] = (ac1+es1*xv)*r1;
    agg[(size_t)v*256 + 128 + lane] = (ac2+es2*xv)*r2;
    agg[(size_t)v*256 + 192 + lane] = (ac3+es3*xv)*r3;
  }
}

// ---------------- K-split dense matmul, 16(or 8) rows/lane, W prefetch ----------------
// MODE 0: out = relu(acc+bias), cols = y*64. MODE 1: atomicAdd. MODE 2 (head): A koff/W cols from z, W rows local.
template<int KC, int J, int RPW, int MODE, bool INREL>
__global__ __launch_bounds__(256) void k_mm3(
    const float* __restrict__ A, int lda,
    const float* __restrict__ W, const float* __restrict__ bias,
    const float* __restrict__ bias_in, float* __restrict__ out){
  constexpr int BR = 4*RPW;
  __shared__ __align__(16) float As[BR*KC];
  const int tid = threadIdx.x;
  const int rb  = blockIdx.x;
  const int akoff   = blockIdx.z*KC;
  const int wkoff   = (MODE==2) ? 0 : blockIdx.z*KC;
  const int colbase = ((MODE==2) ? blockIdx.z*KC : 0) + blockIdx.y*64;

  for (int i = tid; i < BR*KC/4; i += 256){
    int row = i/(KC/4), c4 = (i%(KC/4))*4;
    int grow = rb*BR + row; if (grow >= Nn) grow = Nn-1;
    float4 a4 = *(const float4*)&A[(size_t)grow*lda + akoff + c4];
    if constexpr (INREL){
      float4 b4 = *(const float4*)&bias_in[akoff + c4];
      a4.x = fmaxf(a4.x+b4.x, 0.f);
      a4.y = fmaxf(a4.y+b4.y, 0.f);
      a4.z = fmaxf(a4.z+b4.z, 0.f);
      a4.w = fmaxf(a4.w+b4.w, 0.f);
    }
    *(float4*)&As[row*KC + c4] = a4;
  }
  __syncthreads();

  const int wave = tid >> 6, lane = tid & 63;
  const int r0 = wave*RPW;
  const int col = colbase + lane;
  const float* Wp = W + (size_t)wkoff*J + col;

  float acc[RPW];
  #pragma unroll
  for (int r = 0; r < RPW; ++r) acc[r] = 0.f;

  auto fma_step = [&](int k0, const float* wc){
    #pragma unroll
    for (int r = 0; r < RPW; ++r){
      float4 a4 = *(const float4*)&As[(r0+r)*KC + k0];
      acc[r] = fmaf(a4.x, wc[0], acc[r]);
      acc[r] = fmaf(a4.y, wc[1], acc[r]);
      acc[r] = fmaf(a4.z, wc[2], acc[r]);
      acc[r] = fmaf(a4.w, wc[3], acc[r]);
    }
  };

  float wc[4], wn[4];
  #pragma unroll
  for (int kk = 0; kk < 4; ++kk) wc[kk] = Wp[(size_t)kk*J];
  int k0 = 0;
  for (; k0 + 4 < KC; k0 += 4){
    #pragma unroll
    for (int kk = 0; kk < 4; ++kk) wn[kk] = Wp[(size_t)(k0+4+kk)*J];
    fma_step(k0, wc);
    #pragma unroll
    for (int kk = 0; kk < 4; ++kk) wc[kk] = wn[kk];
  }
  fma_step(k0, wc);

  #pragma unroll
  for (int r = 0; r < RPW; ++r){
    int grow = rb*BR + r0 + r;
    if (grow < Nn){
      size_t oi = (size_t)grow*J + col;
      if constexpr (MODE == 1) atomicAdd(&out[oi], acc[r]);
      else                     out[oi] = fmaxf(acc[r] + bias[col], 0.f);
    }
  }
}

// ---------------- final 128 -> 4 matmul (+bias); A gets relu(A + bias_in) ----------------
__global__ __launch_bounds__(256) void k_mm_fin(
    const float* __restrict__ A, const float* __restrict__ W,
    const float* __restrict__ bias, const float* __restrict__ bias_in,
    float* __restrict__ out){
  int row = blockIdx.x*4 + (threadIdx.x >> 6);
  int lane = threadIdx.x & 63;
  float a0 = fmaxf(A[(size_t)row*128 + lane]      + bias_in[lane],      0.f);
  float a1 = fmaxf(A[(size_t)row*128 + 64 + lane] + bias_in[64 + lane], 0.f);
  float4 w0 = ((const float4*)W)[lane];
  float4 w1 = ((const float4*)W)[64 + lane];
  float p0 = fmaf(a1, w1.x, a0*w0.x);
  float p1 = fmaf(a1, w1.y, a0*w0.y);
  float p2 = fmaf(a1, w1.z, a0*w0.z);
  float p3 = fmaf(a1, w1.w, a0*w0.w);
  #pragma unroll
  for (int off = 32; off; off >>= 1){
    p0 += __shfl_xor(p0, off);
    p1 += __shfl_xor(p1, off);
    p2 += __shfl_xor(p2, off);
    p3 += __shfl_xor(p3, off);
  }
  if (lane == 0){
    float4 bv = *(const float4*)bias;
    *(float4*)&out[(size_t)row*4] = make_float4(p0+bv.x, p1+bv.y, p2+bv.z, p3+bv.w);
  }
}

// ---------------- launch ----------------
extern "C" void kernel_launch(void* const* d_in, const int* in_sizes, int n_in,
                              void* d_out, int out_size, void* d_ws, size_t ws_size,
                              hipStream_t stream){
  const float* x     = (const float*)d_in[0];
  const int*   ei    = (const int*)  d_in[1];
  const float* w_e1  = (const float*)d_in[2];
  const float* b_e1  = (const float*)d_in[3];
  const float* w_e2  = (const float*)d_in[4];
  const float* b_e2  = (const float*)d_in[5];
  const float* w_e3  = (const float*)d_in[6];
  const float* as_e3 = (const float*)d_in[7];
  const float* ad_e3 = (const float*)d_in[8];
  const float* b_e3  = (const float*)d_in[9];
  const float* w_d1  = (const float*)d_in[10];
  const float* b_d1  = (const float*)d_in[11];
  const float* w_d2  = (const float*)d_in[12];
  const float* b_d2  = (const float*)d_in[13];
  const float* w_d3  = (const float*)d_in[14];
  const float* as_d3 = (const float*)d_in[15];
  const float* ad_d3 = (const float*)d_in[16];
  const float* b_d3  = (const float*)d_in[17];
  const float* w_fc1 = (const float*)d_in[18];
  const float* b_fc1 = (const float*)d_in[19];
  const float* w_fc2 = (const float*)d_in[20];
  const float* b_fc2 = (const float*)d_in[21];
  const float* w_fin = (const float*)d_in[22];
  const float* b_fin = (const float*)d_in[23];

  char* ws = (char*)d_ws;
  size_t off = 0;
  auto alloc = [&](size_t bytes)->char*{
    char* p = ws + off;
    off += (bytes + 127) & ~size_t(127);
    return p;
  };
  int*   cnt       = (int*)  alloc((size_t)Nn*4);
  int*   fill      = (int*)  alloc((size_t)Nn*4);
  int*   row_start = (int*)  alloc((size_t)(Nn+1)*4);
  int*   csr       = (int*)  alloc((size_t)Ee*4);
  float* dinv      = (float*)alloc((size_t)Nn*4);
  float* aSb       = (float*)alloc((size_t)Nn*16);
  float* aDb       = (float*)alloc((size_t)Nn*16);
  float* wsF_e3    = (float*)alloc(4*128*4);
  float* wdF_e3    = (float*)alloc(4*128*4);
  float* wsF_d3    = (float*)alloc(4*64*4);
  float* wdF_d3    = (float*)alloc(4*64*4);
  float* X1        = (float*)alloc((size_t)Nn*64*4);
  float* X2        = (float*)alloc((size_t)Nn*128*4);
  float* bufA      = (float*)alloc((size_t)Nn*256*4);
  float* bufB      = (float*)alloc((size_t)Nn*512*4);
  float* bufC      = (float*)alloc((size_t)Nn*512*4);

  const int* srcp = ei;
  const int* dstp = ei + Ee;

  hipMemsetAsync(cnt, 0, (size_t)Nn*4, stream);
  hipMemsetAsync(fill, 0, (size_t)Nn*4, stream);
  k_count<<<(Ee+255)/256, 256, 0, stream>>>(dstp, cnt);
  k_scan<<<1, 1024, 0, stream>>>(cnt, row_start, dinv);
  k_scatter<<<(Ee+255)/256, 256, 0, stream>>>(srcp, dstp, row_start, fill, csr);
  k_fold<128,128><<<1, 256, 0, stream>>>(w_e3, as_e3, ad_e3, wsF_e3, wdF_e3);
  k_fold<64,64><<<1, 256, 0, stream>>>(w_d3, as_d3, ad_d3, wsF_d3, wdF_d3);

  // encoder1: x1 = relu(agg(x) @ W1 + b1)
  k_gcn_agg<32,false><<<Nn/4, 256, 0, stream>>>(x, dinv, row_start, csr, nullptr, nullptr, bufA);
  k_mm3<32,64,8,0,false><<<dim3(625,1,1), 256, 0, stream>>>(bufA, 32, w_e1, b_e1, nullptr, X1);
  // encoder2: x2 = relu(agg(x1) @ W2 + b2)
  k_gcn_agg<64,false><<<Nn/4, 256, 0, stream>>>(X1, dinv, row_start, csr, nullptr, nullptr, bufA);
  k_mm3<64,128,8,0,false><<<dim3(625,2,1), 256, 0, stream>>>(bufA, 64, w_e2, b_e2, nullptr, X2);
  // encoder3 (GAT): x3 = relu(headmm(gat_agg(x2)) + b3)
  k_attn_in<128><<<Nn/4, 256, 0, stream>>>(X2, wsF_e3, wdF_e3, aSb, aDb);
  k_gat_agg_in<128><<<Nn/4, 256, 0, stream>>>(X2, aSb, aDb, row_start, csr, bufB);
  k_mm3<128,512,16,2,false><<<dim3(313,2,4), 256, 0, stream>>>(bufB, 512, w_e3, b_e3, nullptr, bufC);
  // decoder1: h4 = relu(agg(x3 @ Wd1) + bd1) + x2   (K=512 -> 4 atomic chunks)
  hipMemsetAsync(bufA, 0, (size_t)Nn*128*4, stream);
  k_mm3<128,128,16,1,false><<<dim3(313,2,4), 256, 0, stream>>>(bufC, 512, w_d1, nullptr, nullptr, bufA);
  k_gcn_agg<128,true><<<Nn/4, 256, 0, stream>>>(bufA, dinv, row_start, csr, b_d1, X2, bufB);
  // decoder2: h5 = relu(agg(h4 @ Wd2) + bd2) + x1   (K=128 -> 2 atomic chunks)
  hipMemsetAsync(bufC, 0, (size_t)Nn*64*4, stream);
  k_mm3<64,64,8,1,false><<<dim3(625,1,2), 256, 0, stream>>>(bufB, 128, w_d2, nullptr, nullptr, bufC);
  k_gcn_agg<64,true><<<Nn/4, 256, 0, stream>>>(bufC, dinv, row_start, csr, b_d2, X1, bufA);
  // decoder3 (GAT): h6 = relu(headmm(gat_agg(h5)) + bd3)
  k_attn_in<64><<<Nn/4, 256, 0, stream>>>(bufA, wsF_d3, wdF_d3, aSb, aDb);
  k_gat_agg_in<64><<<Nn/4, 256, 0, stream>>>(bufA, aSb, aDb, row_start, csr, bufB);
  k_mm3<64,256,8,2,false><<<dim3(625,1,4), 256, 0, stream>>>(bufB, 256, w_d3, b_d3, nullptr, bufC);
  // MLP head: fc1 (atomic K-split; epilogue fused into fc2's A-stage)
  hipMemsetAsync(bufA, 0, (size_t)Nn*256*4, stream);
  k_mm3<128,256,16,1,false><<<dim3(313,4,2), 256, 0, stream>>>(bufC, 256, w_fc1, nullptr, nullptr, bufA);
  // fc2 (in-relu with b_fc1; atomic K-split; epilogue fused into fin's A-load)
  hipMemsetAsync(bufB, 0, (size_t)Nn*128*4, stream);
  k_mm3<128,128,16,1,true><<<dim3(313,2,2), 256, 0, stream>>>(bufA, 256, w_fc2, nullptr, b_fc1, bufB);
  k_mm_fin<<<Nn/4, 256, 0, stream>>>(bufB, w_fin, b_fin, b_fc2, (float*)d_out);
}

// Round 5
// 401.452 us; speedup vs baseline: 1.7790x; 1.7790x over previous
//
#include <hip/hip_runtime.h>
#include <cstdint>
#include <cstddef>

static constexpr int Nn = 20000;
static constexpr int Ee = 320000;

typedef _Float16 half8 __attribute__((ext_vector_type(8)));
typedef float f32x4 __attribute__((ext_vector_type(4)));

__device__ __forceinline__ float lrelu02(float x){ return fmaxf(x, 0.2f*x); }

// split v = hi + lo/2048, hi/lo fp16 (lo pre-scaled to stay in normal range)
__device__ __forceinline__ void packhl(float v, unsigned short& h, unsigned short& l){
  _Float16 hh = (_Float16)v;
  _Float16 ll = (_Float16)((v - (float)hh) * 2048.0f);
  h = __builtin_bit_cast(unsigned short, hh);
  l = __builtin_bit_cast(unsigned short, ll);
}

// ---------------- CSR build ----------------
__global__ void k_count(const int* __restrict__ dst, int* __restrict__ cnt){
  int e = blockIdx.x*256 + threadIdx.x;
  if (e < Ee) atomicAdd(&cnt[dst[e]], 1);
}

__global__ void k_scan(const int* __restrict__ cnt, int* __restrict__ row_start,
                       float* __restrict__ dinv){
  __shared__ int part[1024];
  int tid = threadIdx.x;
  const int PER = 20;
  int base = tid*PER;
  int s = 0;
  for (int i = 0; i < PER; ++i){ int idx = base+i; if (idx < Nn) s += cnt[idx]; }
  part[tid] = s; __syncthreads();
  for (int off = 1; off < 1024; off <<= 1){
    int v = (tid >= off) ? part[tid-off] : 0;
    __syncthreads();
    part[tid] += v;
    __syncthreads();
  }
  int run = (tid == 0) ? 0 : part[tid-1];
  for (int i = 0; i < PER; ++i){
    int idx = base+i;
    if (idx < Nn){
      row_start[idx] = run;
      int c = cnt[idx];
      run += c;
      dinv[idx] = rsqrtf((float)(c+1));
    }
  }
  if (tid == 1023) row_start[Nn] = run;
}

__global__ void k_scatter(const int* __restrict__ src, const int* __restrict__ dst,
                          const int* __restrict__ row_start, int* __restrict__ fill,
                          int* __restrict__ csr){
  int e = blockIdx.x*256 + threadIdx.x;
  if (e < Ee){
    int d = dst[e];
    int pos = row_start[d] + atomicAdd(&fill[d], 1);
    csr[pos] = src[e];
  }
}

// ---------------- weight hi/lo pre-split: out[0..n)=hi, out[n..2n)=lo ----------------
__global__ void k_packw(const float* __restrict__ W, unsigned short* __restrict__ out, int n){
  int i = blockIdx.x*256 + threadIdx.x;
  if (i < n){
    unsigned short h,l; packhl(W[i],h,l);
    out[i] = h; out[i+n] = l;
  }
}

// ---------------- GCN aggregation (batched gather) ----------------
// POST: 0 = f32 raw; 1 = f32 relu(+bias)+skip; 2 = pack raw; 3 = relu+bias+skip then pack
template<int C, int POST>
__global__ __launch_bounds__(256) void k_gcn_agg(
    const float* __restrict__ h, const float* __restrict__ dinv,
    const int* __restrict__ row_start, const int* __restrict__ csr,
    const float* __restrict__ bias, const float* __restrict__ skip,
    float* __restrict__ outf, unsigned short* __restrict__ outp){
  int v = blockIdx.x*4 + (threadIdx.x >> 6);
  int lane = threadIdx.x & 63;
  int s = row_start[v], e = row_start[v+1];
  float dv = dinv[v];
  const int c = (C==32) ? (lane & 31) : ((C==128) ? lane*2 : lane);

  float a0 = 0.f, a1 = 0.f;
  for (int base = s; base < e; base += 64){
    int i = base + lane;
    int u = 0; float du = 0.f;
    if (i < e){ u = csr[i]; du = dinv[u]; }
    int cnt = min(64, e - base);
    int j = 0;
    for (; j + 4 <= cnt; j += 4){
      int u0=__shfl(u,j), u1=__shfl(u,j+1), u2=__shfl(u,j+2), u3=__shfl(u,j+3);
      float d0=__shfl(du,j), d1=__shfl(du,j+1), d2=__shfl(du,j+2), d3=__shfl(du,j+3);
      if constexpr (C == 128){
        float2 t0 = *(const float2*)&h[(size_t)u0*128 + c];
        float2 t1 = *(const float2*)&h[(size_t)u1*128 + c];
        float2 t2 = *(const float2*)&h[(size_t)u2*128 + c];
        float2 t3 = *(const float2*)&h[(size_t)u3*128 + c];
        a0=fmaf(d0,t0.x,a0); a1=fmaf(d0,t0.y,a1);
        a0=fmaf(d1,t1.x,a0); a1=fmaf(d1,t1.y,a1);
        a0=fmaf(d2,t2.x,a0); a1=fmaf(d2,t2.y,a1);
        a0=fmaf(d3,t3.x,a0); a1=fmaf(d3,t3.y,a1);
      } else {
        float t0 = h[(size_t)u0*C + c];
        float t1 = h[(size_t)u1*C + c];
        float t2 = h[(size_t)u2*C + c];
        float t3 = h[(size_t)u3*C + c];
        a0=fmaf(d0,t0,a0); a0=fmaf(d1,t1,a0); a0=fmaf(d2,t2,a0); a0=fmaf(d3,t3,a0);
      }
    }
    for (; j < cnt; ++j){
      int uj = __shfl(u,j); float dj = __shfl(du,j);
      if constexpr (C == 128){
        float2 t = *(const float2*)&h[(size_t)uj*128 + c];
        a0 = fmaf(dj, t.x, a0); a1 = fmaf(dj, t.y, a1);
      } else {
        a0 = fmaf(dj, h[(size_t)uj*C + c], a0);
      }
    }
  }

  if constexpr (C == 128){
    float2 hv = *(const float2*)&h[(size_t)v*128 + c];
    float vx = fmaf(a0, dv, hv.x*dv*dv);
    float vy = fmaf(a1, dv, hv.y*dv*dv);
    if constexpr (POST & 1){
      float2 bv = *(const float2*)&bias[c];
      float2 sk = *(const float2*)&skip[(size_t)v*128 + c];
      vx = fmaxf(vx + bv.x, 0.f) + sk.x;
      vy = fmaxf(vy + bv.y, 0.f) + sk.y;
    }
    if constexpr (POST & 2){
      unsigned short h0,l0,h1,l1; packhl(vx,h0,l0); packhl(vy,h1,l1);
      *(unsigned int*)&outp[(size_t)v*128 + c] = (unsigned)h0 | ((unsigned)h1<<16);
      *(unsigned int*)&outp[(size_t)v*128 + c + (size_t)Nn*128] = (unsigned)l0 | ((unsigned)l1<<16);
    } else {
      *(float2*)&outf[(size_t)v*128 + c] = make_float2(vx, vy);
    }
  } else if constexpr (C == 64){
    float val = fmaf(a0, dv, h[(size_t)v*64 + c]*dv*dv);
    if constexpr (POST & 1){
      val = fmaxf(val + bias[c], 0.f) + skip[(size_t)v*64 + c];
    }
    if constexpr (POST & 2){
      unsigned short hh,ll; packhl(val,hh,ll);
      outp[(size_t)v*64 + c] = hh;
      outp[(size_t)v*64 + c + (size_t)Nn*64] = ll;
    } else {
      outf[(size_t)v*64 + c] = val;
    }
  } else { // C == 32, pack only
    float val = fmaf(a0, dv, h[(size_t)v*32 + c]*dv*dv);
    if (lane < 32){
      unsigned short hh,ll; packhl(val,hh,ll);
      outp[(size_t)v*32 + c] = hh;
      outp[(size_t)v*32 + c + (size_t)Nn*32] = ll;
    }
  }
}

// ---------------- fold attention vectors through W ----------------
template<int INC, int C>
__global__ void k_fold(const float* __restrict__ W, const float* __restrict__ as_,
                       const float* __restrict__ ad_, float* __restrict__ wsF,
                       float* __restrict__ wdF){
  int h = threadIdx.x >> 6, lane = threadIdx.x & 63;
  for (int k = lane; k < INC; k += 64){
    float s = 0.f, d = 0.f;
    #pragma unroll 4
    for (int c = 0; c < C; ++c){
      float wv = W[(size_t)k*(4*C) + h*C + c];
      s = fmaf(wv, as_[h*C + c], s);
      d = fmaf(wv, ad_[h*C + c], d);
    }
    wsF[h*INC + k] = s;
    wdF[h*INC + k] = d;
  }
}

// ---------------- attention coefficients from the INPUT ----------------
template<int INC>
__global__ __launch_bounds__(256) void k_attn_in(
    const float* __restrict__ X, const float* __restrict__ wsF, const float* __restrict__ wdF,
    float* __restrict__ aS, float* __restrict__ aD){
  int v = blockIdx.x*4 + (threadIdx.x >> 6);
  int lane = threadIdx.x & 63;
  float x0 = X[(size_t)v*INC + lane];
  float x1 = (INC == 128) ? X[(size_t)v*INC + 64 + lane] : 0.f;
  float s[4], d[4];
  #pragma unroll
  for (int h = 0; h < 4; ++h){
    s[h] = x0*wsF[h*INC + lane];
    d[h] = x0*wdF[h*INC + lane];
    if constexpr (INC == 128){
      s[h] = fmaf(x1, wsF[h*INC + 64 + lane], s[h]);
      d[h] = fmaf(x1, wdF[h*INC + 64 + lane], d[h]);
    }
  }
  #pragma unroll
  for (int off = 32; off; off >>= 1){
    #pragma unroll
    for (int h = 0; h < 4; ++h){
      s[h] += __shfl_xor(s[h], off);
      d[h] += __shfl_xor(d[h], off);
    }
  }
  if (lane == 0){
    *(float4*)&aS[v*4] = make_float4(s[0], s[1], s[2], s[3]);
    *(float4*)&aD[v*4] = make_float4(d[0], d[1], d[2], d[3]);
  }
}

// ---------------- GAT aggregation (batched, single-pass), packs output ----------------
template<int INC>   // 128 (e3) or 64 (d3)
__global__ __launch_bounds__(256) void k_gat_agg_in(
    const float* __restrict__ X, const float* __restrict__ aS, const float* __restrict__ aD,
    const int* __restrict__ row_start, const int* __restrict__ csr,
    unsigned short* __restrict__ outp){
  int v = blockIdx.x*4 + (threadIdx.x >> 6);
  int lane = threadIdx.x & 63;
  int s0 = row_start[v], e0 = row_start[v+1];

  float4 tD = *(const float4*)&aD[v*4];
  float ad0=tD.x, ad1=tD.y, ad2=tD.z, ad3=tD.w;
  float4 tS = *(const float4*)&aS[v*4];
  float ls0=lrelu02(tS.x+ad0), ls1=lrelu02(tS.y+ad1), ls2=lrelu02(tS.z+ad2), ls3=lrelu02(tS.w+ad3);

  float m0=ls0, m1=ls1, m2=ls2, m3=ls3;
  for (int i = s0 + lane; i < e0; i += 64){
    int u = csr[i];
    float4 a4 = *(const float4*)&aS[u*4];
    m0 = fmaxf(m0, lrelu02(a4.x+ad0));
    m1 = fmaxf(m1, lrelu02(a4.y+ad1));
    m2 = fmaxf(m2, lrelu02(a4.z+ad2));
    m3 = fmaxf(m3, lrelu02(a4.w+ad3));
  }
  #pragma unroll
  for (int off = 32; off; off >>= 1){
    m0 = fmaxf(m0, __shfl_xor(m0, off));
    m1 = fmaxf(m1, __shfl_xor(m1, off));
    m2 = fmaxf(m2, __shfl_xor(m2, off));
    m3 = fmaxf(m3, __shfl_xor(m3, off));
  }

  float sd0=0.f, sd1=0.f, sd2=0.f, sd3=0.f;
  float2 acc0={0,0}, acc1={0,0}, acc2={0,0}, acc3={0,0};
  float ac0=0.f, ac1=0.f, ac2=0.f, ac3=0.f;
  const int c2 = lane*2;

  for (int base = s0; base < e0; base += 64){
    int i = base + lane;
    int u = 0; float e0v=0.f, e1v=0.f, e2v=0.f, e3v=0.f;
    if (i < e0){
      u = csr[i];
      float4 a4 = *(const float4*)&aS[u*4];
      e0v = __expf(lrelu02(a4.x+ad0) - m0);
      e1v = __expf(lrelu02(a4.y+ad1) - m1);
      e2v = __expf(lrelu02(a4.z+ad2) - m2);
      e3v = __expf(lrelu02(a4.w+ad3) - m3);
      sd0 += e0v; sd1 += e1v; sd2 += e2v; sd3 += e3v;
    }
    int cnt = min(64, e0 - base);
    #pragma unroll 2
    for (int j = 0; j < cnt; ++j){
      int uj = __shfl(u, j);
      float f0=__shfl(e0v,j), f1=__shfl(e1v,j), f2=__shfl(e2v,j), f3=__shfl(e3v,j);
      if constexpr (INC == 128){
        float2 xu = *(const float2*)&X[(size_t)uj*128 + c2];
        acc0.x=fmaf(f0,xu.x,acc0.x); acc0.y=fmaf(f0,xu.y,acc0.y);
        acc1.x=fmaf(f1,xu.x,acc1.x); acc1.y=fmaf(f1,xu.y,acc1.y);
        acc2.x=fmaf(f2,xu.x,acc2.x); acc2.y=fmaf(f2,xu.y,acc2.y);
        acc3.x=fmaf(f3,xu.x,acc3.x); acc3.y=fmaf(f3,xu.y,acc3.y);
      } else {
        float xu = X[(size_t)uj*64 + lane];
        ac0=fmaf(f0,xu,ac0); ac1=fmaf(f1,xu,ac1); ac2=fmaf(f2,xu,ac2); ac3=fmaf(f3,xu,ac3);
      }
    }
  }

  #pragma unroll
  for (int off = 32; off; off >>= 1){
    sd0 += __shfl_xor(sd0, off);
    sd1 += __shfl_xor(sd1, off);
    sd2 += __shfl_xor(sd2, off);
    sd3 += __shfl_xor(sd3, off);
  }
  float es0=__expf(ls0-m0), es1=__expf(ls1-m1), es2=__expf(ls2-m2), es3=__expf(ls3-m3);
  float r0=1.f/(sd0+es0), r1=1.f/(sd1+es1), r2=1.f/(sd2+es2), r3=1.f/(sd3+es3);

  if constexpr (INC == 128){
    float2 xv = *(const float2*)&X[(size_t)v*128 + c2];
    const size_t loOff = (size_t)Nn*512;
    float ox, oy; unsigned short h0,l0,h1,l1;
    ox=(acc0.x+es0*xv.x)*r0; oy=(acc0.y+es0*xv.y)*r0;
    packhl(ox,h0,l0); packhl(oy,h1,l1);
    *(unsigned int*)&outp[(size_t)v*512 +   0 + c2] = (unsigned)h0|((unsigned)h1<<16);
    *(unsigned int*)&outp[(size_t)v*512 +   0 + c2 + loOff] = (unsigned)l0|((unsigned)l1<<16);
    ox=(acc1.x+es1*xv.x)*r1; oy=(acc1.y+es1*xv.y)*r1;
    packhl(ox,h0,l0); packhl(oy,h1,l1);
    *(unsigned int*)&outp[(size_t)v*512 + 128 + c2] = (unsigned)h0|((unsigned)h1<<16);
    *(unsigned int*)&outp[(size_t)v*512 + 128 + c2 + loOff] = (unsigned)l0|((unsigned)l1<<16);
    ox=(acc2.x+es2*xv.x)*r2; oy=(acc2.y+es2*xv.y)*r2;
    packhl(ox,h0,l0); packhl(oy,h1,l1);
    *(unsigned int*)&outp[(size_t)v*512 + 256 + c2] = (unsigned)h0|((unsigned)h1<<16);
    *(unsigned int*)&outp[(size_t)v*512 + 256 + c2 + loOff] = (unsigned)l0|((unsigned)l1<<16);
    ox=(acc3.x+es3*xv.x)*r3; oy=(acc3.y+es3*xv.y)*r3;
    packhl(ox,h0,l0); packhl(oy,h1,l1);
    *(unsigned int*)&outp[(size_t)v*512 + 384 + c2] = (unsigned)h0|((unsigned)h1<<16);
    *(unsigned int*)&outp[(size_t)v*512 + 384 + c2 + loOff] = (unsigned)l0|((unsigned)l1<<16);
  } else {
    float xv = X[(size_t)v*64 + lane];
    const size_t loOff = (size_t)Nn*256;
    unsigned short hh,ll;
    float o;
    o = (ac0+es0*xv)*r0; packhl(o,hh,ll);
    outp[(size_t)v*256 +   0 + lane] = hh; outp[(size_t)v*256 +   0 + lane + loOff] = ll;
    o = (ac1+es1*xv)*r1; packhl(o,hh,ll);
    outp[(size_t)v*256 +  64 + lane] = hh; outp[(size_t)v*256 +  64 + lane + loOff] = ll;
    o = (ac2+es2*xv)*r2; packhl(o,hh,ll);
    outp[(size_t)v*256 + 128 + lane] = hh; outp[(size_t)v*256 + 128 + lane + loOff] = ll;
    o = (ac3+es3*xv)*r3; packhl(o,hh,ll);
    outp[(size_t)v*256 + 192 + lane] = hh; outp[(size_t)v*256 + 192 + lane + loOff] = ll;
  }
}

// ---------------- MFMA GEMM with fp16 hi/lo split (3 MFMAs per tile-product) ----------------
// out[n, z*Jh + j] = sum_k A[n, z*K + k] * W[k, z*Jh + j]  (HEADS = J/Jh; HEADS=1 => plain GEMM)
// A packed: hi u16 [Nn][lda], lo at +Nn*lda.  W packed: hi u16 [K][J], lo at +K*J.
// EPI: 0 = f32 raw; 1 = f32 relu(acc+bias); 2 = relu(acc+bias) then pack (lo at +Nn*J)
// BM=32, BN=64, BK=32; block 256 = 4 waves (wave w: rows (w&1)*16.., colfrags (w>>1)*2..)
template<int K, int J, int Jh, int EPI>
__global__ __launch_bounds__(256) void k_gemm(
    const unsigned short* __restrict__ Ahi, int lda,
    const unsigned short* __restrict__ Whi,
    const float* __restrict__ bias,
    float* __restrict__ outf, unsigned short* __restrict__ outp){
  __shared__ unsigned short sAhi[2*64*8], sAlo[2*64*8];
  __shared__ unsigned short sBhi[4*64*8], sBlo[4*64*8];

  const int tid  = threadIdx.x;
  const int lane = tid & 63, w = tid >> 6;
  const int rh = w & 1, ch = w >> 1;
  const int rb = blockIdx.x;
  const int colbase = blockIdx.z*Jh + blockIdx.y*64;
  const int akoff   = blockIdx.z*K;
  const size_t AloOff = (size_t)Nn*lda;
  const size_t WloOff = (size_t)K*J;

  f32x4 accH0 = {0,0,0,0}, accH1 = {0,0,0,0};
  f32x4 accM0 = {0,0,0,0}, accM1 = {0,0,0,0};

  // staging maps
  const int arow = tid >> 3;              // 0..31
  const int ak4  = (tid & 7) * 4;         // 0..28
  const int aw_idx = (((arow>>4)*4 + (ak4>>3))*16 + (arow&15))*8 + (ak4&4);
  const unsigned short* Ag = Ahi + (size_t)(rb*32 + arow)*lda + akoff + ak4;
  const int bcol = tid & 63;
  const int bkg  = tid >> 6;              // 0..3
  const int bw_idx = (((bcol>>4)*4 + bkg)*16 + (bcol&15))*8;
  const unsigned short* Wg = Whi + colbase + bcol;

  #pragma unroll 1
  for (int ks = 0; ks < K/32; ++ks){
    if (ks) __syncthreads();
    { // stage A (32 rows x 32 k), frag-ordered
      const unsigned short* p = Ag + ks*32;
      uint2 hv = *(const uint2*)p;
      uint2 lv = *(const uint2*)(p + AloOff);
      *(uint2*)&sAhi[aw_idx] = hv;
      *(uint2*)&sAlo[aw_idx] = lv;
    }
    { // stage B (32 k x 64 col), frag-ordered
      const unsigned short* p = Wg + (size_t)(ks*32 + bkg*8)*J;
      unsigned short h[8], l[8];
      #pragma unroll
      for (int i = 0; i < 8; ++i){
        h[i] = p[(size_t)i*J];
        l[i] = p[(size_t)i*J + WloOff];
      }
      uint4 hv, lv;
      hv.x = (unsigned)h[0]|((unsigned)h[1]<<16); hv.y = (unsigned)h[2]|((unsigned)h[3]<<16);
      hv.z = (unsigned)h[4]|((unsigned)h[5]<<16); hv.w = (unsigned)h[6]|((unsigned)h[7]<<16);
      lv.x = (unsigned)l[0]|((unsigned)l[1]<<16); lv.y = (unsigned)l[2]|((unsigned)l[3]<<16);
      lv.z = (unsigned)l[4]|((unsigned)l[5]<<16); lv.w = (unsigned)l[6]|((unsigned)l[7]<<16);
      *(uint4*)&sBhi[bw_idx] = hv;
      *(uint4*)&sBlo[bw_idx] = lv;
    }
    __syncthreads();

    half8 aH = *(const half8*)&sAhi[(rh*64 + lane)*8];
    half8 aL = *(const half8*)&sAlo[(rh*64 + lane)*8];
    {
      int cf = ch*2;
      half8 bH = *(const half8*)&sBhi[(cf*64 + lane)*8];
      half8 bL = *(const half8*)&sBlo[(cf*64 + lane)*8];
      accH0 = __builtin_amdgcn_mfma_f32_16x16x32_f16(aH, bH, accH0, 0, 0, 0);
      accM0 = __builtin_amdgcn_mfma_f32_16x16x32_f16(aH, bL, accM0, 0, 0, 0);
      accM0 = __builtin_amdgcn_mfma_f32_16x16x32_f16(aL, bH, accM0, 0, 0, 0);
    }
    {
      int cf = ch*2 + 1;
      half8 bH = *(const half8*)&sBhi[(cf*64 + lane)*8];
      half8 bL = *(const half8*)&sBlo[(cf*64 + lane)*8];
      accH1 = __builtin_amdgcn_mfma_f32_16x16x32_f16(aH, bH, accH1, 0, 0, 0);
      accM1 = __builtin_amdgcn_mfma_f32_16x16x32_f16(aH, bL, accM1, 0, 0, 0);
      accM1 = __builtin_amdgcn_mfma_f32_16x16x32_f16(aL, bH, accM1, 0, 0, 0);
    }
  }

  // epilogue: C/D layout col = lane&15, row = (lane>>4)*4 + r  [HW-verified]
  #pragma unroll
  for (int q = 0; q < 2; ++q){
    int cf = ch*2 + q;
    int col = colbase + cf*16 + (lane & 15);
    float bv = (EPI >= 1) ? bias[col] : 0.f;
    const f32x4& aH = q ? accH1 : accH0;
    const f32x4& aM = q ? accM1 : accM0;
    #pragma unroll
    for (int r = 0; r < 4; ++r){
      int row = rb*32 + rh*16 + ((lane>>4)*4 + r);
      float v = aH[r] + aM[r]*(1.0f/2048.0f);
      if constexpr (EPI >= 1) v = fmaxf(v + bv, 0.f);
      if constexpr (EPI == 2){
        unsigned short hh, ll; packhl(v, hh, ll);
        outp[(size_t)row*J + col] = hh;
        outp[(size_t)row*J + col + (size_t)Nn*J] = ll;
      } else {
        outf[(size_t)row*J + col] = v;
      }
    }
  }
}

// ---------------- final 128 -> 4 matmul (+bias), one wave per row ----------------
__global__ __launch_bounds__(256) void k_mm_fin(
    const float* __restrict__ A, const float* __restrict__ W,
    const float* __restrict__ bias, float* __restrict__ out){
  int row = blockIdx.x*4 + (threadIdx.x >> 6);
  int lane = threadIdx.x & 63;
  float a0 = A[(size_t)row*128 + lane];
  float a1 = A[(size_t)row*128 + 64 + lane];
  float4 w0 = ((const float4*)W)[lane];
  float4 w1 = ((const float4*)W)[64 + lane];
  float p0 = fmaf(a1, w1.x, a0*w0.x);
  float p1 = fmaf(a1, w1.y, a0*w0.y);
  float p2 = fmaf(a1, w1.z, a0*w0.z);
  float p3 = fmaf(a1, w1.w, a0*w0.w);
  #pragma unroll
  for (int off = 32; off; off >>= 1){
    p0 += __shfl_xor(p0, off);
    p1 += __shfl_xor(p1, off);
    p2 += __shfl_xor(p2, off);
    p3 += __shfl_xor(p3, off);
  }
  if (lane == 0){
    float4 bv = *(const float4*)bias;
    *(float4*)&out[(size_t)row*4] = make_float4(p0+bv.x, p1+bv.y, p2+bv.z, p3+bv.w);
  }
}

// ---------------- launch ----------------
extern "C" void kernel_launch(void* const* d_in, const int* in_sizes, int n_in,
                              void* d_out, int out_size, void* d_ws, size_t ws_size,
                              hipStream_t stream){
  const float* x     = (const float*)d_in[0];
  const int*   ei    = (const int*)  d_in[1];
  const float* w_e1  = (const float*)d_in[2];
  const float* b_e1  = (const float*)d_in[3];
  const float* w_e2  = (const float*)d_in[4];
  const float* b_e2  = (const float*)d_in[5];
  const float* w_e3  = (const float*)d_in[6];
  const float* as_e3 = (const float*)d_in[7];
  const float* ad_e3 = (const float*)d_in[8];
  const float* b_e3  = (const float*)d_in[9];
  const float* w_d1  = (const float*)d_in[10];
  const float* b_d1  = (const float*)d_in[11];
  const float* w_d2  = (const float*)d_in[12];
  const float* b_d2  = (const float*)d_in[13];
  const float* w_d3  = (const float*)d_in[14];
  const float* as_d3 = (const float*)d_in[15];
  const float* ad_d3 = (const float*)d_in[16];
  const float* b_d3  = (const float*)d_in[17];
  const float* w_fc1 = (const float*)d_in[18];
  const float* b_fc1 = (const float*)d_in[19];
  const float* w_fc2 = (const float*)d_in[20];
  const float* b_fc2 = (const float*)d_in[21];
  const float* w_fin = (const float*)d_in[22];
  const float* b_fin = (const float*)d_in[23];

  char* ws = (char*)d_ws;
  size_t off = 0;
  auto alloc = [&](size_t bytes)->char*{
    char* p = ws + off;
    off += (bytes + 127) & ~size_t(127);
    return p;
  };
  int*   cnt       = (int*)  alloc((size_t)Nn*4);
  int*   fill      = (int*)  alloc((size_t)Nn*4);
  int*   row_start = (int*)  alloc((size_t)(Nn+1)*4);
  int*   csr       = (int*)  alloc((size_t)Ee*4);
  float* dinv      = (float*)alloc((size_t)Nn*4);
  float* aSb       = (float*)alloc((size_t)Nn*16);
  float* aDb       = (float*)alloc((size_t)Nn*16);
  float* wsF_e3    = (float*)alloc(4*128*4);
  float* wdF_e3    = (float*)alloc(4*128*4);
  float* wsF_d3    = (float*)alloc(4*64*4);
  float* wdF_d3    = (float*)alloc(4*64*4);
  // packed weights (hi then lo)
  unsigned short* wp_e1  = (unsigned short*)alloc((size_t)32*64*4);
  unsigned short* wp_e2  = (unsigned short*)alloc((size_t)64*128*4);
  unsigned short* wp_e3  = (unsigned short*)alloc((size_t)128*512*4);
  unsigned short* wp_d1  = (unsigned short*)alloc((size_t)512*128*4);
  unsigned short* wp_d2  = (unsigned short*)alloc((size_t)128*64*4);
  unsigned short* wp_d3  = (unsigned short*)alloc((size_t)64*256*4);
  unsigned short* wp_fc1 = (unsigned short*)alloc((size_t)256*256*4);
  unsigned short* wp_fc2 = (unsigned short*)alloc((size_t)256*128*4);
  // activations
  unsigned short* P0 = (unsigned short*)alloc((size_t)Nn*32*4);   // e1 input packed
  float* X1 = (float*)alloc((size_t)Nn*64*4);
  float* X2 = (float*)alloc((size_t)Nn*128*4);
  unsigned short* S1 = (unsigned short*)alloc((size_t)Nn*512*4);  // 41 MB slab
  unsigned short* S2 = (unsigned short*)alloc((size_t)Nn*512*4);  // 41 MB slab
  char*  S3 = alloc((size_t)Nn*128*4);                            // 10.24 MB slab

  const int* srcp = ei;
  const int* dstp = ei + Ee;

  hipMemsetAsync(cnt, 0, (size_t)Nn*4, stream);
  hipMemsetAsync(fill, 0, (size_t)Nn*4, stream);
  k_count<<<(Ee+255)/256, 256, 0, stream>>>(dstp, cnt);
  k_scan<<<1, 1024, 0, stream>>>(cnt, row_start, dinv);
  k_scatter<<<(Ee+255)/256, 256, 0, stream>>>(srcp, dstp, row_start, fill, csr);
  k_fold<128,128><<<1, 256, 0, stream>>>(w_e3, as_e3, ad_e3, wsF_e3, wdF_e3);
  k_fold<64,64><<<1, 256, 0, stream>>>(w_d3, as_d3, ad_d3, wsF_d3, wdF_d3);
  // pre-split weights
  k_packw<<<  8, 256, 0, stream>>>(w_e1,  wp_e1,  32*64);
  k_packw<<< 32, 256, 0, stream>>>(w_e2,  wp_e2,  64*128);
  k_packw<<<256, 256, 0, stream>>>(w_e3,  wp_e3,  128*512);
  k_packw<<<256, 256, 0, stream>>>(w_d1,  wp_d1,  512*128);
  k_packw<<< 32, 256, 0, stream>>>(w_d2,  wp_d2,  128*64);
  k_packw<<< 64, 256, 0, stream>>>(w_d3,  wp_d3,  64*256);
  k_packw<<<256, 256, 0, stream>>>(w_fc1, wp_fc1, 256*256);
  k_packw<<<128, 256, 0, stream>>>(w_fc2, wp_fc2, 256*128);

  // encoder1: x1 = relu(agg(x) @ W1 + b1)
  k_gcn_agg<32,2><<<Nn/4, 256, 0, stream>>>(x, dinv, row_start, csr, nullptr, nullptr, nullptr, P0);
  k_gemm<32,64,64,1><<<dim3(625,1,1), 256, 0, stream>>>(P0, 32, wp_e1, b_e1, X1, nullptr);
  // encoder2: x2 = relu(agg(x1) @ W2 + b2)
  k_gcn_agg<64,2><<<Nn/4, 256, 0, stream>>>(X1, dinv, row_start, csr, nullptr, nullptr, nullptr, (unsigned short*)S3);
  k_gemm<64,128,128,1><<<dim3(625,2,1), 256, 0, stream>>>((unsigned short*)S3, 64, wp_e2, b_e2, X2, nullptr);
  // encoder3 (GAT): x3 = relu(headmm(gat_agg(x2)) + b3)
  k_attn_in<128><<<Nn/4, 256, 0, stream>>>(X2, wsF_e3, wdF_e3, aSb, aDb);
  k_gat_agg_in<128><<<Nn/4, 256, 0, stream>>>(X2, aSb, aDb, row_start, csr, S1);
  k_gemm<128,512,128,2><<<dim3(625,2,4), 256, 0, stream>>>(S1, 512, wp_e3, b_e3, nullptr, S2);
  // decoder1: h4 = relu(agg(x3 @ Wd1) + bd1) + x2
  k_gemm<512,128,128,0><<<dim3(625,2,1), 256, 0, stream>>>(S2, 512, wp_d1, nullptr, (float*)S3, nullptr);
  k_gcn_agg<128,3><<<Nn/4, 256, 0, stream>>>((float*)S3, dinv, row_start, csr, b_d1, X2, nullptr, S1);
  // decoder2: h5 = relu(agg(h4 @ Wd2) + bd2) + x1
  k_gemm<128,64,64,0><<<dim3(625,1,1), 256, 0, stream>>>(S1, 128, wp_d2, nullptr, (float*)S2, nullptr);
  k_gcn_agg<64,1><<<Nn/4, 256, 0, stream>>>((float*)S2, dinv, row_start, csr, b_d2, X1, (float*)S3, nullptr);
  // decoder3 (GAT): h6 = relu(headmm(gat_agg(h5)) + bd3)
  k_attn_in<64><<<Nn/4, 256, 0, stream>>>((float*)S3, wsF_d3, wdF_d3, aSb, aDb);
  k_gat_agg_in<64><<<Nn/4, 256, 0, stream>>>((float*)S3, aSb, aDb, row_start, csr, S1);
  k_gemm<64,256,64,2><<<dim3(625,1,4), 256, 0, stream>>>(S1, 256, wp_d3, b_d3, nullptr, S2);
  // MLP head
  k_gemm<256,256,256,2><<<dim3(625,4,1), 256, 0, stream>>>(S2, 256, wp_fc1, b_fc1, nullptr, S1);
  k_gemm<256,128,128,1><<<dim3(625,2,1), 256, 0, stream>>>(S1, 256, wp_fc2, b_fc2, (float*)S2, nullptr);
  k_mm_fin<<<Nn/4, 256, 0, stream>>>((float*)S2, w_fin, b_fin, (float*)d_out);
}

// Round 6
// 396.223 us; speedup vs baseline: 1.8025x; 1.0132x over previous
//
#include <hip/hip_runtime.h>
#include <cstdint>
#include <cstddef>

static constexpr int Nn = 20000;
static constexpr int Ee = 320000;

typedef _Float16 half8 __attribute__((ext_vector_type(8)));
typedef float f32x4 __attribute__((ext_vector_type(4)));

__device__ __forceinline__ float lrelu02(float x){ return fmaxf(x, 0.2f*x); }
__device__ __forceinline__ float af(int x){ return __int_as_float(x); }

// split v = hi + lo/2048, hi/lo fp16 (lo pre-scaled to stay in normal range)
__device__ __forceinline__ void packhl(float v, unsigned short& h, unsigned short& l){
  _Float16 hh = (_Float16)v;
  _Float16 ll = (_Float16)((v - (float)hh) * 2048.0f);
  h = __builtin_bit_cast(unsigned short, hh);
  l = __builtin_bit_cast(unsigned short, ll);
}

// ---------------- CSR build ----------------
__global__ void k_count(const int* __restrict__ dst, int* __restrict__ cnt){
  int e = blockIdx.x*256 + threadIdx.x;
  if (e < Ee) atomicAdd(&cnt[dst[e]], 1);
}

__global__ void k_scan(const int* __restrict__ cnt, int* __restrict__ row_start,
                       float* __restrict__ dinv){
  __shared__ int part[1024];
  int tid = threadIdx.x;
  const int PER = 20;
  int base = tid*PER;
  int s = 0;
  for (int i = 0; i < PER; ++i){ int idx = base+i; if (idx < Nn) s += cnt[idx]; }
  part[tid] = s; __syncthreads();
  for (int off = 1; off < 1024; off <<= 1){
    int v = (tid >= off) ? part[tid-off] : 0;
    __syncthreads();
    part[tid] += v;
    __syncthreads();
  }
  int run = (tid == 0) ? 0 : part[tid-1];
  for (int i = 0; i < PER; ++i){
    int idx = base+i;
    if (idx < Nn){
      row_start[idx] = run;
      int c = cnt[idx];
      run += c;
      dinv[idx] = rsqrtf((float)(c+1));
    }
  }
  if (tid == 1023) row_start[Nn] = run;
}

__global__ void k_scatter(const int* __restrict__ src, const int* __restrict__ dst,
                          const int* __restrict__ row_start, int* __restrict__ fill,
                          int* __restrict__ csr){
  int e = blockIdx.x*256 + threadIdx.x;
  if (e < Ee){
    int d = dst[e];
    int pos = row_start[d] + atomicAdd(&fill[d], 1);
    csr[pos] = src[e];
  }
}

// ---------------- GCN edge records {u, dinv[u]} ----------------
__global__ void k_erec(const int* __restrict__ csr, const float* __restrict__ dinv,
                       int2* __restrict__ erec){
  int i = blockIdx.x*256 + threadIdx.x;
  if (i < Ee){
    int u = csr[i];
    erec[i] = make_int2(u, __float_as_int(dinv[u]));
  }
}

// ---------------- fragment-packed weight split ----------------
// layout: pos = ((cf*(K/8) + g)*16 + c15)*8 + j,  cf=col/16, c15=col%16, g=k/8, j=k%8
// hi at [0, K*J), lo at [K*J, 2*K*J)
template<int K, int J>
__global__ void k_packwf(const float* __restrict__ W, unsigned short* __restrict__ out){
  int i = blockIdx.x*256 + threadIdx.x;
  if (i < K*J){
    int k = i / J, col = i - k*J;
    unsigned short h, l; packhl(W[i], h, l);
    size_t pos = ((size_t)((col>>4)*(K/8) + (k>>3))*16 + (col&15))*8 + (k&7);
    out[pos] = h;
    out[pos + (size_t)K*J] = l;
  }
}

// ---------------- GCN aggregation (uniform record loads) ----------------
// POST: 0 = f32 raw; 1 = f32 relu(+bias)+skip; 2 = pack raw; 3 = relu+bias+skip then pack
template<int C, int POST>
__global__ __launch_bounds__(256) void k_gcn_agg(
    const float* __restrict__ h, const float* __restrict__ dinv,
    const int* __restrict__ row_start, const int2* __restrict__ erec,
    const float* __restrict__ bias, const float* __restrict__ skip,
    float* __restrict__ outf, unsigned short* __restrict__ outp){
  int v = blockIdx.x*4 + (threadIdx.x >> 6);
  int lane = threadIdx.x & 63;
  int s = __builtin_amdgcn_readfirstlane(row_start[v]);
  int e = __builtin_amdgcn_readfirstlane(row_start[v+1]);
  float dv = dinv[v];
  const int c = (C==32) ? (lane & 31) : ((C==128) ? lane*2 : lane);

  float a0 = 0.f, a1 = 0.f;
  if constexpr (C == 32){
    // half-wave: half h processes edges s+h, s+h+2, ...
    int half = lane >> 5;
    int j = s + half;
    for (; j + 2 < e; j += 4){
      int2 r0 = erec[j], r1 = erec[j+2];
      float t0 = h[(size_t)r0.x*32 + c];
      float t1 = h[(size_t)r1.x*32 + c];
      a0 = fmaf(af(r0.y), t0, a0);
      a0 = fmaf(af(r1.y), t1, a0);
    }
    if (j < e){
      int2 r0 = erec[j];
      a0 = fmaf(af(r0.y), h[(size_t)r0.x*32 + c], a0);
    }
    a0 += __shfl_xor(a0, 32);
  } else if constexpr (C == 128){
    int j = s;
    for (; j + 4 <= e; j += 4){
      int2 r0 = erec[j], r1 = erec[j+1], r2 = erec[j+2], r3 = erec[j+3];
      float2 t0 = *(const float2*)&h[(size_t)r0.x*128 + c];
      float2 t1 = *(const float2*)&h[(size_t)r1.x*128 + c];
      float2 t2 = *(const float2*)&h[(size_t)r2.x*128 + c];
      float2 t3 = *(const float2*)&h[(size_t)r3.x*128 + c];
      a0=fmaf(af(r0.y),t0.x,a0); a1=fmaf(af(r0.y),t0.y,a1);
      a0=fmaf(af(r1.y),t1.x,a0); a1=fmaf(af(r1.y),t1.y,a1);
      a0=fmaf(af(r2.y),t2.x,a0); a1=fmaf(af(r2.y),t2.y,a1);
      a0=fmaf(af(r3.y),t3.x,a0); a1=fmaf(af(r3.y),t3.y,a1);
    }
    for (; j < e; ++j){
      int2 r = erec[j];
      float2 t = *(const float2*)&h[(size_t)r.x*128 + c];
      a0 = fmaf(af(r.y), t.x, a0); a1 = fmaf(af(r.y), t.y, a1);
    }
  } else { // C == 64
    int j = s;
    for (; j + 4 <= e; j += 4){
      int2 r0 = erec[j], r1 = erec[j+1], r2 = erec[j+2], r3 = erec[j+3];
      float t0 = h[(size_t)r0.x*64 + c];
      float t1 = h[(size_t)r1.x*64 + c];
      float t2 = h[(size_t)r2.x*64 + c];
      float t3 = h[(size_t)r3.x*64 + c];
      a0=fmaf(af(r0.y),t0,a0); a0=fmaf(af(r1.y),t1,a0);
      a0=fmaf(af(r2.y),t2,a0); a0=fmaf(af(r3.y),t3,a0);
    }
    for (; j < e; ++j){
      int2 r = erec[j];
      a0 = fmaf(af(r.y), h[(size_t)r.x*64 + c], a0);
    }
  }

  if constexpr (C == 128){
    float2 hv = *(const float2*)&h[(size_t)v*128 + c];
    float vx = fmaf(a0, dv, hv.x*dv*dv);
    float vy = fmaf(a1, dv, hv.y*dv*dv);
    if constexpr (POST & 1){
      float2 bv = *(const float2*)&bias[c];
      float2 sk = *(const float2*)&skip[(size_t)v*128 + c];
      vx = fmaxf(vx + bv.x, 0.f) + sk.x;
      vy = fmaxf(vy + bv.y, 0.f) + sk.y;
    }
    if constexpr (POST & 2){
      unsigned short h0,l0,h1,l1; packhl(vx,h0,l0); packhl(vy,h1,l1);
      *(unsigned int*)&outp[(size_t)v*128 + c] = (unsigned)h0 | ((unsigned)h1<<16);
      *(unsigned int*)&outp[(size_t)v*128 + c + (size_t)Nn*128] = (unsigned)l0 | ((unsigned)l1<<16);
    } else {
      *(float2*)&outf[(size_t)v*128 + c] = make_float2(vx, vy);
    }
  } else if constexpr (C == 64){
    float val = fmaf(a0, dv, h[(size_t)v*64 + c]*dv*dv);
    if constexpr (POST & 1){
      val = fmaxf(val + bias[c], 0.f) + skip[(size_t)v*64 + c];
    }
    if constexpr (POST & 2){
      unsigned short hh,ll; packhl(val,hh,ll);
      outp[(size_t)v*64 + c] = hh;
      outp[(size_t)v*64 + c + (size_t)Nn*64] = ll;
    } else {
      outf[(size_t)v*64 + c] = val;
    }
  } else { // C == 32, pack only
    float val = fmaf(a0, dv, h[(size_t)v*32 + c]*dv*dv);
    if (lane < 32){
      unsigned short hh,ll; packhl(val,hh,ll);
      outp[(size_t)v*32 + c] = hh;
      outp[(size_t)v*32 + c + (size_t)Nn*32] = ll;
    }
  }
}

// ---------------- fold attention vectors through W ----------------
template<int INC, int C>
__global__ void k_fold(const float* __restrict__ W, const float* __restrict__ as_,
                       const float* __restrict__ ad_, float* __restrict__ wsF,
                       float* __restrict__ wdF){
  int h = threadIdx.x >> 6, lane = threadIdx.x & 63;
  for (int k = lane; k < INC; k += 64){
    float s = 0.f, d = 0.f;
    #pragma unroll 4
    for (int c = 0; c < C; ++c){
      float wv = W[(size_t)k*(4*C) + h*C + c];
      s = fmaf(wv, as_[h*C + c], s);
      d = fmaf(wv, ad_[h*C + c], d);
    }
    wsF[h*INC + k] = s;
    wdF[h*INC + k] = d;
  }
}

// ---------------- attention coefficients from the INPUT ----------------
template<int INC>
__global__ __launch_bounds__(256) void k_attn_in(
    const float* __restrict__ X, const float* __restrict__ wsF, const float* __restrict__ wdF,
    float* __restrict__ aS, float* __restrict__ aD){
  int v = blockIdx.x*4 + (threadIdx.x >> 6);
  int lane = threadIdx.x & 63;
  float x0 = X[(size_t)v*INC + lane];
  float x1 = (INC == 128) ? X[(size_t)v*INC + 64 + lane] : 0.f;
  float s[4], d[4];
  #pragma unroll
  for (int h = 0; h < 4; ++h){
    s[h] = x0*wsF[h*INC + lane];
    d[h] = x0*wdF[h*INC + lane];
    if constexpr (INC == 128){
      s[h] = fmaf(x1, wsF[h*INC + 64 + lane], s[h]);
      d[h] = fmaf(x1, wdF[h*INC + 64 + lane], d[h]);
    }
  }
  #pragma unroll
  for (int off = 32; off; off >>= 1){
    #pragma unroll
    for (int h = 0; h < 4; ++h){
      s[h] += __shfl_xor(s[h], off);
      d[h] += __shfl_xor(d[h], off);
    }
  }
  if (lane == 0){
    *(float4*)&aS[v*4] = make_float4(s[0], s[1], s[2], s[3]);
    *(float4*)&aD[v*4] = make_float4(d[0], d[1], d[2], d[3]);
  }
}

// ---------------- GAT prep: per-edge unnormalized exps + per-vertex self-f and 1/denom ----------------
__global__ __launch_bounds__(256) void k_gat_prep(
    const float* __restrict__ aS, const float* __restrict__ aD,
    const int* __restrict__ row_start, const int* __restrict__ csr,
    float4* __restrict__ alphaE, float4* __restrict__ fS4, float4* __restrict__ rin4){
  int v = blockIdx.x*4 + (threadIdx.x >> 6);
  int lane = threadIdx.x & 63;
  int s = row_start[v], e = row_start[v+1];

  float4 tD = *(const float4*)&aD[v*4];
  float ad0=tD.x, ad1=tD.y, ad2=tD.z, ad3=tD.w;
  float4 tS = *(const float4*)&aS[v*4];
  float ls0=lrelu02(tS.x+ad0), ls1=lrelu02(tS.y+ad1), ls2=lrelu02(tS.z+ad2), ls3=lrelu02(tS.w+ad3);

  float m0=ls0, m1=ls1, m2=ls2, m3=ls3;
  for (int i = s + lane; i < e; i += 64){
    int u = csr[i];
    float4 a4 = *(const float4*)&aS[u*4];
    m0 = fmaxf(m0, lrelu02(a4.x+ad0));
    m1 = fmaxf(m1, lrelu02(a4.y+ad1));
    m2 = fmaxf(m2, lrelu02(a4.z+ad2));
    m3 = fmaxf(m3, lrelu02(a4.w+ad3));
  }
  #pragma unroll
  for (int off = 32; off; off >>= 1){
    m0 = fmaxf(m0, __shfl_xor(m0, off));
    m1 = fmaxf(m1, __shfl_xor(m1, off));
    m2 = fmaxf(m2, __shfl_xor(m2, off));
    m3 = fmaxf(m3, __shfl_xor(m3, off));
  }

  float sd0=0.f, sd1=0.f, sd2=0.f, sd3=0.f;
  for (int i = s + lane; i < e; i += 64){
    int u = csr[i];
    float4 a4 = *(const float4*)&aS[u*4];
    float f0 = __expf(lrelu02(a4.x+ad0) - m0);
    float f1 = __expf(lrelu02(a4.y+ad1) - m1);
    float f2 = __expf(lrelu02(a4.z+ad2) - m2);
    float f3 = __expf(lrelu02(a4.w+ad3) - m3);
    sd0 += f0; sd1 += f1; sd2 += f2; sd3 += f3;
    alphaE[i] = make_float4(f0, f1, f2, f3);
  }
  #pragma unroll
  for (int off = 32; off; off >>= 1){
    sd0 += __shfl_xor(sd0, off);
    sd1 += __shfl_xor(sd1, off);
    sd2 += __shfl_xor(sd2, off);
    sd3 += __shfl_xor(sd3, off);
  }
  if (lane == 0){
    float es0=__expf(ls0-m0), es1=__expf(ls1-m1), es2=__expf(ls2-m2), es3=__expf(ls3-m3);
    fS4[v] = make_float4(es0, es1, es2, es3);
    rin4[v] = make_float4(1.f/(sd0+es0), 1.f/(sd1+es1), 1.f/(sd2+es2), 1.f/(sd3+es3));
  }
}

// ---------------- GAT aggregation v2: uniform record loads, packs output ----------------
template<int INC>   // 128 (e3) or 64 (d3)
__global__ __launch_bounds__(256) void k_gat_agg2(
    const float* __restrict__ X, const int* __restrict__ csr,
    const float4* __restrict__ alphaE, const float4* __restrict__ fS4,
    const float4* __restrict__ rin4, const int* __restrict__ row_start,
    unsigned short* __restrict__ outp){
  int v = blockIdx.x*4 + (threadIdx.x >> 6);
  int lane = threadIdx.x & 63;
  int s = __builtin_amdgcn_readfirstlane(row_start[v]);
  int e = __builtin_amdgcn_readfirstlane(row_start[v+1]);
  const int c2 = lane*2;

  float2 acc0={0,0}, acc1={0,0}, acc2={0,0}, acc3={0,0};
  float ac0=0.f, ac1=0.f, ac2=0.f, ac3=0.f;

  int j = s;
  for (; j + 4 <= e; j += 4){
    int u0=csr[j], u1=csr[j+1], u2=csr[j+2], u3=csr[j+3];
    float4 f0=alphaE[j], f1=alphaE[j+1], f2=alphaE[j+2], f3=alphaE[j+3];
    if constexpr (INC == 128){
      float2 x0 = *(const float2*)&X[(size_t)u0*128 + c2];
      float2 x1 = *(const float2*)&X[(size_t)u1*128 + c2];
      float2 x2 = *(const float2*)&X[(size_t)u2*128 + c2];
      float2 x3 = *(const float2*)&X[(size_t)u3*128 + c2];
      acc0.x=fmaf(f0.x,x0.x,acc0.x); acc0.y=fmaf(f0.x,x0.y,acc0.y);
      acc1.x=fmaf(f0.y,x0.x,acc1.x); acc1.y=fmaf(f0.y,x0.y,acc1.y);
      acc2.x=fmaf(f0.z,x0.x,acc2.x); acc2.y=fmaf(f0.z,x0.y,acc2.y);
      acc3.x=fmaf(f0.w,x0.x,acc3.x); acc3.y=fmaf(f0.w,x0.y,acc3.y);
      acc0.x=fmaf(f1.x,x1.x,acc0.x); acc0.y=fmaf(f1.x,x1.y,acc0.y);
      acc1.x=fmaf(f1.y,x1.x,acc1.x); acc1.y=fmaf(f1.y,x1.y,acc1.y);
      acc2.x=fmaf(f1.z,x1.x,acc2.x); acc2.y=fmaf(f1.z,x1.y,acc2.y);
      acc3.x=fmaf(f1.w,x1.x,acc3.x); acc3.y=fmaf(f1.w,x1.y,acc3.y);
      acc0.x=fmaf(f2.x,x2.x,acc0.x); acc0.y=fmaf(f2.x,x2.y,acc0.y);
      acc1.x=fmaf(f2.y,x2.x,acc1.x); acc1.y=fmaf(f2.y,x2.y,acc1.y);
      acc2.x=fmaf(f2.z,x2.x,acc2.x); acc2.y=fmaf(f2.z,x2.y,acc2.y);
      acc3.x=fmaf(f2.w,x2.x,acc3.x); acc3.y=fmaf(f2.w,x2.y,acc3.y);
      acc0.x=fmaf(f3.x,x3.x,acc0.x); acc0.y=fmaf(f3.x,x3.y,acc0.y);
      acc1.x=fmaf(f3.y,x3.x,acc1.x); acc1.y=fmaf(f3.y,x3.y,acc1.y);
      acc2.x=fmaf(f3.z,x3.x,acc2.x); acc2.y=fmaf(f3.z,x3.y,acc2.y);
      acc3.x=fmaf(f3.w,x3.x,acc3.x); acc3.y=fmaf(f3.w,x3.y,acc3.y);
    } else {
      float x0 = X[(size_t)u0*64 + lane];
      float x1 = X[(size_t)u1*64 + lane];
      float x2 = X[(size_t)u2*64 + lane];
      float x3 = X[(size_t)u3*64 + lane];
      ac0=fmaf(f0.x,x0,ac0); ac1=fmaf(f0.y,x0,ac1); ac2=fmaf(f0.z,x0,ac2); ac3=fmaf(f0.w,x0,ac3);
      ac0=fmaf(f1.x,x1,ac0); ac1=fmaf(f1.y,x1,ac1); ac2=fmaf(f1.z,x1,ac2); ac3=fmaf(f1.w,x1,ac3);
      ac0=fmaf(f2.x,x2,ac0); ac1=fmaf(f2.y,x2,ac1); ac2=fmaf(f2.z,x2,ac2); ac3=fmaf(f2.w,x2,ac3);
      ac0=fmaf(f3.x,x3,ac0); ac1=fmaf(f3.y,x3,ac1); ac2=fmaf(f3.z,x3,ac2); ac3=fmaf(f3.w,x3,ac3);
    }
  }
  for (; j < e; ++j){
    int u = csr[j];
    float4 f = alphaE[j];
    if constexpr (INC == 128){
      float2 xu = *(const float2*)&X[(size_t)u*128 + c2];
      acc0.x=fmaf(f.x,xu.x,acc0.x); acc0.y=fmaf(f.x,xu.y,acc0.y);
      acc1.x=fmaf(f.y,xu.x,acc1.x); acc1.y=fmaf(f.y,xu.y,acc1.y);
      acc2.x=fmaf(f.z,xu.x,acc2.x); acc2.y=fmaf(f.z,xu.y,acc2.y);
      acc3.x=fmaf(f.w,xu.x,acc3.x); acc3.y=fmaf(f.w,xu.y,acc3.y);
    } else {
      float xu = X[(size_t)u*64 + lane];
      ac0=fmaf(f.x,xu,ac0); ac1=fmaf(f.y,xu,ac1); ac2=fmaf(f.z,xu,ac2); ac3=fmaf(f.w,xu,ac3);
    }
  }

  float4 fs = fS4[v];
  float4 rv = rin4[v];

  if constexpr (INC == 128){
    float2 xv = *(const float2*)&X[(size_t)v*128 + c2];
    const size_t loOff = (size_t)Nn*512;
    float ox, oy; unsigned short h0,l0,h1,l1;
    ox=(acc0.x+fs.x*xv.x)*rv.x; oy=(acc0.y+fs.x*xv.y)*rv.x;
    packhl(ox,h0,l0); packhl(oy,h1,l1);
    *(unsigned int*)&outp[(size_t)v*512 +   0 + c2] = (unsigned)h0|((unsigned)h1<<16);
    *(unsigned int*)&outp[(size_t)v*512 +   0 + c2 + loOff] = (unsigned)l0|((unsigned)l1<<16);
    ox=(acc1.x+fs.y*xv.x)*rv.y; oy=(acc1.y+fs.y*xv.y)*rv.y;
    packhl(ox,h0,l0); packhl(oy,h1,l1);
    *(unsigned int*)&outp[(size_t)v*512 + 128 + c2] = (unsigned)h0|((unsigned)h1<<16);
    *(unsigned int*)&outp[(size_t)v*512 + 128 + c2 + loOff] = (unsigned)l0|((unsigned)l1<<16);
    ox=(acc2.x+fs.z*xv.x)*rv.z; oy=(acc2.y+fs.z*xv.y)*rv.z;
    packhl(ox,h0,l0); packhl(oy,h1,l1);
    *(unsigned int*)&outp[(size_t)v*512 + 256 + c2] = (unsigned)h0|((unsigned)h1<<16);
    *(unsigned int*)&outp[(size_t)v*512 + 256 + c2 + loOff] = (unsigned)l0|((unsigned)l1<<16);
    ox=(acc3.x+fs.w*xv.x)*rv.w; oy=(acc3.y+fs.w*xv.y)*rv.w;
    packhl(ox,h0,l0); packhl(oy,h1,l1);
    *(unsigned int*)&outp[(size_t)v*512 + 384 + c2] = (unsigned)h0|((unsigned)h1<<16);
    *(unsigned int*)&outp[(size_t)v*512 + 384 + c2 + loOff] = (unsigned)l0|((unsigned)l1<<16);
  } else {
    float xv = X[(size_t)v*64 + lane];
    const size_t loOff = (size_t)Nn*256;
    unsigned short hh,ll;
    float o;
    o = (ac0+fs.x*xv)*rv.x; packhl(o,hh,ll);
    outp[(size_t)v*256 +   0 + lane] = hh; outp[(size_t)v*256 +   0 + lane + loOff] = ll;
    o = (ac1+fs.y*xv)*rv.y; packhl(o,hh,ll);
    outp[(size_t)v*256 +  64 + lane] = hh; outp[(size_t)v*256 +  64 + lane + loOff] = ll;
    o = (ac2+fs.z*xv)*rv.z; packhl(o,hh,ll);
    outp[(size_t)v*256 + 128 + lane] = hh; outp[(size_t)v*256 + 128 + lane + loOff] = ll;
    o = (ac3+fs.w*xv)*rv.w; packhl(o,hh,ll);
    outp[(size_t)v*256 + 192 + lane] = hh; outp[(size_t)v*256 + 192 + lane + loOff] = ll;
  }
}

// ---------------- MFMA GEMM, fp16 hi/lo split, fragment-packed W ----------------
// out[n, z*Jh + j] = sum_k A[n, z*K + k] * W[k, z*Jh + j]
// A packed: hi u16 [Nn][lda], lo at +Nn*lda.  W fragment-packed (k_packwf), lo at +K*J.
// EPI: 0 = f32 raw; 1 = f32 relu(acc+bias); 2 = relu(acc+bias) then pack (lo at +Nn*J)
template<int K, int J, int Jh, int EPI>
__global__ __launch_bounds__(256) void k_gemm(
    const unsigned short* __restrict__ Ahi, int lda,
    const unsigned short* __restrict__ Wp,
    const float* __restrict__ bias,
    float* __restrict__ outf, unsigned short* __restrict__ outp){
  __shared__ unsigned short sAhi[2*64*8], sAlo[2*64*8];
  __shared__ unsigned short sBhi[4*64*8], sBlo[4*64*8];

  const int tid  = threadIdx.x;
  const int lane = tid & 63, w = tid >> 6;
  const int rh = w & 1, ch = w >> 1;
  const int rb = blockIdx.x;
  const int colbase = blockIdx.z*Jh + blockIdx.y*64;
  const int akoff   = blockIdx.z*K;
  const size_t AloOff = (size_t)Nn*lda;
  const size_t WloOff = (size_t)K*J;

  f32x4 accH0 = {0,0,0,0}, accH1 = {0,0,0,0};
  f32x4 accM0 = {0,0,0,0}, accM1 = {0,0,0,0};

  // A staging map
  const int arow = tid >> 3;
  const int ak4  = (tid & 7) * 4;
  const int aw_idx = (((arow>>4)*4 + (ak4>>3))*16 + (arow&15))*8 + (ak4&4);
  const unsigned short* Ag = Ahi + (size_t)(rb*32 + arow)*lda + akoff + ak4;
  // B staging map (fragment-packed W): one uint4 per buffer per k-step
  const int bcol = tid & 63;
  const int bkg  = tid >> 6;
  const int bw_idx = (((bcol>>4)*4 + bkg)*16 + (bcol&15))*8;
  const int cf_g  = (colbase>>4) + (bcol>>4);
  const size_t wbase = ((size_t)cf_g*(K/8)*16 + (size_t)(bcol&15))*8;

  #pragma unroll 1
  for (int ks = 0; ks < K/32; ++ks){
    if (ks) __syncthreads();
    { // stage A
      const unsigned short* p = Ag + ks*32;
      uint2 hv = *(const uint2*)p;
      uint2 lv = *(const uint2*)(p + AloOff);
      *(uint2*)&sAhi[aw_idx] = hv;
      *(uint2*)&sAlo[aw_idx] = lv;
    }
    { // stage B (coalesced uint4 from fragment-packed W)
      size_t goff = wbase + (size_t)(ks*4 + bkg)*16*8;
      uint4 hv = *(const uint4*)&Wp[goff];
      uint4 lv = *(const uint4*)&Wp[goff + WloOff];
      *(uint4*)&sBhi[bw_idx] = hv;
      *(uint4*)&sBlo[bw_idx] = lv;
    }
    __syncthreads();

    half8 aH = *(const half8*)&sAhi[(rh*64 + lane)*8];
    half8 aL = *(const half8*)&sAlo[(rh*64 + lane)*8];
    {
      int cf = ch*2;
      half8 bH = *(const half8*)&sBhi[(cf*64 + lane)*8];
      half8 bL = *(const half8*)&sBlo[(cf*64 + lane)*8];
      accH0 = __builtin_amdgcn_mfma_f32_16x16x32_f16(aH, bH, accH0, 0, 0, 0);
      accM0 = __builtin_amdgcn_mfma_f32_16x16x32_f16(aH, bL, accM0, 0, 0, 0);
      accM0 = __builtin_amdgcn_mfma_f32_16x16x32_f16(aL, bH, accM0, 0, 0, 0);
    }
    {
      int cf = ch*2 + 1;
      half8 bH = *(const half8*)&sBhi[(cf*64 + lane)*8];
      half8 bL = *(const half8*)&sBlo[(cf*64 + lane)*8];
      accH1 = __builtin_amdgcn_mfma_f32_16x16x32_f16(aH, bH, accH1, 0, 0, 0);
      accM1 = __builtin_amdgcn_mfma_f32_16x16x32_f16(aH, bL, accM1, 0, 0, 0);
      accM1 = __builtin_amdgcn_mfma_f32_16x16x32_f16(aL, bH, accM1, 0, 0, 0);
    }
  }

  // epilogue: C/D layout col = lane&15, row = (lane>>4)*4 + r
  #pragma unroll
  for (int q = 0; q < 2; ++q){
    int cf = ch*2 + q;
    int col = colbase + cf*16 + (lane & 15);
    float bv = (EPI >= 1) ? bias[col] : 0.f;
    const f32x4& aH = q ? accH1 : accH0;
    const f32x4& aM = q ? accM1 : accM0;
    #pragma unroll
    for (int r = 0; r < 4; ++r){
      int row = rb*32 + rh*16 + ((lane>>4)*4 + r);
      float v = aH[r] + aM[r]*(1.0f/2048.0f);
      if constexpr (EPI >= 1) v = fmaxf(v + bv, 0.f);
      if constexpr (EPI == 2){
        unsigned short hh, ll; packhl(v, hh, ll);
        outp[(size_t)row*J + col] = hh;
        outp[(size_t)row*J + col + (size_t)Nn*J] = ll;
      } else {
        outf[(size_t)row*J + col] = v;
      }
    }
  }
}

// ---------------- final 128 -> 4 matmul (+bias), one wave per row ----------------
__global__ __launch_bounds__(256) void k_mm_fin(
    const float* __restrict__ A, const float* __restrict__ W,
    const float* __restrict__ bias, float* __restrict__ out){
  int row = blockIdx.x*4 + (threadIdx.x >> 6);
  int lane = threadIdx.x & 63;
  float a0 = A[(size_t)row*128 + lane];
  float a1 = A[(size_t)row*128 + 64 + lane];
  float4 w0 = ((const float4*)W)[lane];
  float4 w1 = ((const float4*)W)[64 + lane];
  float p0 = fmaf(a1, w1.x, a0*w0.x);
  float p1 = fmaf(a1, w1.y, a0*w0.y);
  float p2 = fmaf(a1, w1.z, a0*w0.z);
  float p3 = fmaf(a1, w1.w, a0*w0.w);
  #pragma unroll
  for (int off = 32; off; off >>= 1){
    p0 += __shfl_xor(p0, off);
    p1 += __shfl_xor(p1, off);
    p2 += __shfl_xor(p2, off);
    p3 += __shfl_xor(p3, off);
  }
  if (lane == 0){
    float4 bv = *(const float4*)bias;
    *(float4*)&out[(size_t)row*4] = make_float4(p0+bv.x, p1+bv.y, p2+bv.z, p3+bv.w);
  }
}

// ---------------- launch ----------------
extern "C" void kernel_launch(void* const* d_in, const int* in_sizes, int n_in,
                              void* d_out, int out_size, void* d_ws, size_t ws_size,
                              hipStream_t stream){
  const float* x     = (const float*)d_in[0];
  const int*   ei    = (const int*)  d_in[1];
  const float* w_e1  = (const float*)d_in[2];
  const float* b_e1  = (const float*)d_in[3];
  const float* w_e2  = (const float*)d_in[4];
  const float* b_e2  = (const float*)d_in[5];
  const float* w_e3  = (const float*)d_in[6];
  const float* as_e3 = (const float*)d_in[7];
  const float* ad_e3 = (const float*)d_in[8];
  const float* b_e3  = (const float*)d_in[9];
  const float* w_d1  = (const float*)d_in[10];
  const float* b_d1  = (const float*)d_in[11];
  const float* w_d2  = (const float*)d_in[12];
  const float* b_d2  = (const float*)d_in[13];
  const float* w_d3  = (const float*)d_in[14];
  const float* as_d3 = (const float*)d_in[15];
  const float* ad_d3 = (const float*)d_in[16];
  const float* b_d3  = (const float*)d_in[17];
  const float* w_fc1 = (const float*)d_in[18];
  const float* b_fc1 = (const float*)d_in[19];
  const float* w_fc2 = (const float*)d_in[20];
  const float* b_fc2 = (const float*)d_in[21];
  const float* w_fin = (const float*)d_in[22];
  const float* b_fin = (const float*)d_in[23];

  char* ws = (char*)d_ws;
  size_t off = 0;
  auto alloc = [&](size_t bytes)->char*{
    char* p = ws + off;
    off += (bytes + 127) & ~size_t(127);
    return p;
  };
  int*   cnt       = (int*)  alloc((size_t)Nn*4);
  int*   fill      = (int*)  alloc((size_t)Nn*4);
  int*   row_start = (int*)  alloc((size_t)(Nn+1)*4);
  int*   csr       = (int*)  alloc((size_t)Ee*4);
  float* dinv      = (float*)alloc((size_t)Nn*4);
  int2*  erec      = (int2*) alloc((size_t)Ee*8);
  float4* alphaE   = (float4*)alloc((size_t)Ee*16);
  float4* fS4      = (float4*)alloc((size_t)Nn*16);
  float4* rin4     = (float4*)alloc((size_t)Nn*16);
  float* aSb       = (float*)alloc((size_t)Nn*16);
  float* aDb       = (float*)alloc((size_t)Nn*16);
  float* wsF_e3    = (float*)alloc(4*128*4);
  float* wdF_e3    = (float*)alloc(4*128*4);
  float* wsF_d3    = (float*)alloc(4*64*4);
  float* wdF_d3    = (float*)alloc(4*64*4);
  // fragment-packed weights (hi then lo)
  unsigned short* wp_e1  = (unsigned short*)alloc((size_t)32*64*4);
  unsigned short* wp_e2  = (unsigned short*)alloc((size_t)64*128*4);
  unsigned short* wp_e3  = (unsigned short*)alloc((size_t)128*512*4);
  unsigned short* wp_d1  = (unsigned short*)alloc((size_t)512*128*4);
  unsigned short* wp_d2  = (unsigned short*)alloc((size_t)128*64*4);
  unsigned short* wp_d3  = (unsigned short*)alloc((size_t)64*256*4);
  unsigned short* wp_fc1 = (unsigned short*)alloc((size_t)256*256*4);
  unsigned short* wp_fc2 = (unsigned short*)alloc((size_t)256*128*4);
  // activations
  unsigned short* P0 = (unsigned short*)alloc((size_t)Nn*32*4);
  float* X1 = (float*)alloc((size_t)Nn*64*4);
  float* X2 = (float*)alloc((size_t)Nn*128*4);
  unsigned short* S1 = (unsigned short*)alloc((size_t)Nn*512*4);
  unsigned short* S2 = (unsigned short*)alloc((size_t)Nn*512*4);
  char*  S3 = alloc((size_t)Nn*128*4);

  const int* srcp = ei;
  const int* dstp = ei + Ee;

  hipMemsetAsync(cnt, 0, (size_t)Nn*4, stream);
  hipMemsetAsync(fill, 0, (size_t)Nn*4, stream);
  k_count<<<(Ee+255)/256, 256, 0, stream>>>(dstp, cnt);
  k_scan<<<1, 1024, 0, stream>>>(cnt, row_start, dinv);
  k_scatter<<<(Ee+255)/256, 256, 0, stream>>>(srcp, dstp, row_start, fill, csr);
  k_erec<<<(Ee+255)/256, 256, 0, stream>>>(csr, dinv, erec);
  k_fold<128,128><<<1, 256, 0, stream>>>(w_e3, as_e3, ad_e3, wsF_e3, wdF_e3);
  k_fold<64,64><<<1, 256, 0, stream>>>(w_d3, as_d3, ad_d3, wsF_d3, wdF_d3);
  // fragment-pack weights
  k_packwf<32,64>  <<<  8, 256, 0, stream>>>(w_e1,  wp_e1);
  k_packwf<64,128> <<< 32, 256, 0, stream>>>(w_e2,  wp_e2);
  k_packwf<128,512><<<256, 256, 0, stream>>>(w_e3,  wp_e3);
  k_packwf<512,128><<<256, 256, 0, stream>>>(w_d1,  wp_d1);
  k_packwf<128,64> <<< 32, 256, 0, stream>>>(w_d2,  wp_d2);
  k_packwf<64,256> <<< 64, 256, 0, stream>>>(w_d3,  wp_d3);
  k_packwf<256,256><<<256, 256, 0, stream>>>(w_fc1, wp_fc1);
  k_packwf<256,128><<<128, 256, 0, stream>>>(w_fc2, wp_fc2);

  // encoder1: x1 = relu(agg(x) @ W1 + b1)
  k_gcn_agg<32,2><<<Nn/4, 256, 0, stream>>>(x, dinv, row_start, erec, nullptr, nullptr, nullptr, P0);
  k_gemm<32,64,64,1><<<dim3(625,1,1), 256, 0, stream>>>(P0, 32, wp_e1, b_e1, X1, nullptr);
  // encoder2: x2 = relu(agg(x1) @ W2 + b2)
  k_gcn_agg<64,2><<<Nn/4, 256, 0, stream>>>(X1, dinv, row_start, erec, nullptr, nullptr, nullptr, (unsigned short*)S3);
  k_gemm<64,128,128,1><<<dim3(625,2,1), 256, 0, stream>>>((unsigned short*)S3, 64, wp_e2, b_e2, X2, nullptr);
  // encoder3 (GAT): x3 = relu(headmm(gat_agg(x2)) + b3)
  k_attn_in<128><<<Nn/4, 256, 0, stream>>>(X2, wsF_e3, wdF_e3, aSb, aDb);
  k_gat_prep<<<Nn/4, 256, 0, stream>>>(aSb, aDb, row_start, csr, alphaE, fS4, rin4);
  k_gat_agg2<128><<<Nn/4, 256, 0, stream>>>(X2, csr, alphaE, fS4, rin4, row_start, S1);
  k_gemm<128,512,128,2><<<dim3(625,2,4), 256, 0, stream>>>(S1, 512, wp_e3, b_e3, nullptr, S2);
  // decoder1: h4 = relu(agg(x3 @ Wd1) + bd1) + x2
  k_gemm<512,128,128,0><<<dim3(625,2,1), 256, 0, stream>>>(S2, 512, wp_d1, nullptr, (float*)S3, nullptr);
  k_gcn_agg<128,3><<<Nn/4, 256, 0, stream>>>((float*)S3, dinv, row_start, erec, b_d1, X2, nullptr, S1);
  // decoder2: h5 = relu(agg(h4 @ Wd2) + bd2) + x1
  k_gemm<128,64,64,0><<<dim3(625,1,1), 256, 0, stream>>>(S1, 128, wp_d2, nullptr, (float*)S2, nullptr);
  k_gcn_agg<64,1><<<Nn/4, 256, 0, stream>>>((float*)S2, dinv, row_start, erec, b_d2, X1, (float*)S3, nullptr);
  // decoder3 (GAT): h6 = relu(headmm(gat_agg(h5)) + bd3)
  k_attn_in<64><<<Nn/4, 256, 0, stream>>>((float*)S3, wsF_d3, wdF_d3, aSb, aDb);
  k_gat_prep<<<Nn/4, 256, 0, stream>>>(aSb, aDb, row_start, csr, alphaE, fS4, rin4);
  k_gat_agg2<64><<<Nn/4, 256, 0, stream>>>((float*)S3, csr, alphaE, fS4, rin4, row_start, S1);
  k_gemm<64,256,64,2><<<dim3(625,1,4), 256, 0, stream>>>(S1, 256, wp_d3, b_d3, nullptr, S2);
  // MLP head
  k_gemm<256,256,256,2><<<dim3(625,4,1), 256, 0, stream>>>(S2, 256, wp_fc1, b_fc1, nullptr, S1);
  k_gemm<256,128,128,1><<<dim3(625,2,1), 256, 0, stream>>>(S1, 256, wp_fc2, b_fc2, (float*)S2, nullptr);
  k_mm_fin<<<Nn/4, 256, 0, stream>>>((float*)S2, w_fin, b_fin, (float*)d_out);
}